// Round 16
// baseline (39.372 us; speedup 1.0000x reference)
//
#include <hip/hip_runtime.h>

// B*H*W = 65536 vectors, dim 64, 512 codes
#define NVEC 65536
#define DIM 64
#define KCODES 512
#define VPB 128       // vectors per block
#define NBLK 512      // NVEC / VPB
#define ELS 2048.0f   // residual pre-scale (avoids fp16 denormals)
#define INV_ELS (1.0f / 2048.0f)
#define BIAS 8.0f     // score bias -> positive floats, uint-sortable
#define GAP_THR 2.5e-4f // rescore guard: > 2x (split-fp16 1.5e-5 + 5-bit mask 3e-5)

typedef _Float16 f16x8 __attribute__((ext_vector_type(8)));
typedef float    f32x4 __attribute__((ext_vector_type(4)));
typedef unsigned long long u64;

// ws layout (floats):
#define WS_EN   4                   // [4..516) codebook norms (exact)
#define WS_EH   1024                // [1024..17408) hi fp16 B-fragments (pre-scaled by -2)
#define WS_EL   (1024 + 16384)      // [17408..33792) residual fp16 B-fragments (pre-scaled by -2*ELS)
#define WS_PART 33792               // [33792..34304) per-block loss partials (512)
#define WS_EMBT 34816               // [34816..67584) embT[k][d]

// Prep (17 blocks x 512): b=0 exact norms; b=1..8 MFMA B-fragments with the
// -2 factor folded in (exact: *2 lossless in fp16); b=9..16 emb -> embT.
__global__ __launch_bounds__(512, 1) void prep_kernel(const float* __restrict__ emb,
                                                      float* __restrict__ ws) {
    const int tid = threadIdx.x;
    const int b   = blockIdx.x;
    if (b == 0) {
        float s = 0.f;
#pragma unroll
        for (int d = 0; d < DIM; ++d) { float v = emb[d * KCODES + tid]; s = fmaf(v, v, s); }
        ws[WS_EN + tid] = s;
    } else if (b <= 8) {
        const int fl = (b - 1) * 512 + tid;            // fragment-lane id, 0..4095
        const int ct = fl >> 7, s5 = (fl >> 6) & 1, l = fl & 63;
        const int k  = ct * 16 + (l & 15);             // B col
        const int d0 = s5 * 32 + (l >> 4) * 8;         // B k-rows (d)
        f16x8 eh, el;
#pragma unroll
        for (int e = 0; e < 8; ++e) {
            float v = emb[(d0 + e) * KCODES + k];
            _Float16 h = (_Float16)v;
            _Float16 l16 = (_Float16)((v - (float)h) * ELS);
            eh[e] = -(h + h);      // -2*h, exact
            el[e] = -(l16 + l16);  // -2*l, exact
        }
        ((f16x8*)(ws + WS_EH))[fl] = eh;
        ((f16x8*)(ws + WS_EL))[fl] = el;
    } else {
        __shared__ float tl[64][65];
        const int kt = b - 9;          // k-tile 0..7
        const int r  = tid >> 3;       // 0..63
        const int g  = tid & 7;
#pragma unroll
        for (int i = 0; i < 8; ++i)
            tl[r][g * 8 + i] = emb[r * KCODES + kt * 64 + g * 8 + i];
        __syncthreads();
#pragma unroll
        for (int i = 0; i < 8; ++i)
            ws[WS_EMBT + (kt * 64 + r) * 64 + g * 8 + i] = tl[g * 8 + i][r];
    }
}

// Main: 512 thr = 8 waves, VPB=128, grid 512 -> 4096 waves = 4 waves/SIMD in
// ONE occupancy round. Wave pair (wid>>1) owns M=32 vectors (two 16-row MFMA
// A-sets); wid&1 selects a 256-code half-stream (16 tiles) -> per-CU fragment
// traffic HALVED vs R15 (the measured binder) at unchanged wave count and
// unchanged per-wave score-update count. Packed-u32 top-2 (6 inst/score),
// swap-free 2-deep pipeline, u64 lex merge across 16 lanes, cross-half LDS
// lex merge (half-0 owns lower k), exact fp32 rescore when masked gap <=
// GAP_THR; embT epilogue; no atomics.
__global__ __launch_bounds__(512, 4) void vq_kernel(const float* __restrict__ x,
                                                    const float* __restrict__ ws_ro,
                                                    float* __restrict__ out,
                                                    float* __restrict__ part) {
    __shared__ f16x8 zhS[VPB][8];   // [v][u], u = (d>>3) ^ (v&7)  (bank swizzle)
    __shared__ f16x8 zlS[VPB][8];
    __shared__ float enS8[KCODES];  // en + BIAS (scan C-init)
    __shared__ float sdf1[2][VPB], sdf2[2][VPB];   // per-half biased masked scores
    __shared__ int   k1a[2][VPB],  k2a[2][VPB];
    __shared__ int   cand[VPB][2];
    __shared__ float sdfm[VPB][2];
    __shared__ float exd[VPB][2];
    __shared__ int   bksel[VPB];
    __shared__ float swl[8];

    const int tid  = threadIdx.x;
    const int wid  = tid >> 6;            // 0..7
    const int lane = tid & 63;
    const size_t xbase = (size_t)blockIdx.x * VPB * DIM;

    enS8[tid] = ws_ro[WS_EN + tid] + BIAS;   // biased copy for the scan

    // x-block -> fp16 hi + scaled residual into swizzled LDS (4 thr/vector)
    {
        const int v  = tid >> 2;          // 0..127
        const int d0 = (tid & 3) * 16;
        const float* xp = x + xbase + v * DIM + d0;
        float4 a = *(const float4*)(xp);
        float4 b = *(const float4*)(xp + 4);
        float4 c = *(const float4*)(xp + 8);
        float4 e = *(const float4*)(xp + 12);
        float t0[8] = {a.x, a.y, a.z, a.w, b.x, b.y, b.z, b.w};
        float t1[8] = {c.x, c.y, c.z, c.w, e.x, e.y, e.z, e.w};
        f16x8 h0, l0, h1, l1;
#pragma unroll
        for (int i = 0; i < 8; ++i) {
            _Float16 h = (_Float16)t0[i]; h0[i] = h; l0[i] = (_Float16)((t0[i] - (float)h) * ELS);
            _Float16 g = (_Float16)t1[i]; h1[i] = g; l1[i] = (_Float16)((t1[i] - (float)g) * ELS);
        }
        const int u0 = ((d0 >> 3))     ^ (v & 7);
        const int u1 = ((d0 >> 3) + 1) ^ (v & 7);
        zhS[v][u0] = h0; zhS[v][u1] = h1;
        zlS[v][u0] = l0; zlS[v][u1] = l1;
    }
    __syncthreads();

    // A-fragments for TWO 16-row sets: rows vb..vb+15 and vb+16..vb+31
    const int half = wid & 1;             // code half: 0 -> k<256, 1 -> k>=256
    const int vb   = (wid >> 1) * 32;
    const int col  = lane & 15;
    const int g4   = lane >> 4;
    const int vA0  = vb + col,      sw0 = vA0 & 7;
    const int vA1  = vb + 16 + col, sw1 = vA1 & 7;
    f16x8 ah0_0 = zhS[vA0][(g4)     ^ sw0];
    f16x8 ah1_0 = zhS[vA0][(4 + g4) ^ sw0];
    f16x8 al0_0 = zlS[vA0][(g4)     ^ sw0];
    f16x8 al1_0 = zlS[vA0][(4 + g4) ^ sw0];
    f16x8 ah0_1 = zhS[vA1][(g4)     ^ sw1];
    f16x8 ah1_1 = zhS[vA1][(4 + g4) ^ sw1];
    f16x8 al0_1 = zlS[vA1][(g4)     ^ sw1];
    f16x8 al1_1 = zlS[vA1][(4 + g4) ^ sw1];

    const f16x8* ehp = (const f16x8*)(ws_ro + WS_EH);
    const f16x8* elp = (const f16x8*)(ws_ro + WS_EL);
    const int fb = half * 2048;           // fragment base of this half (16 tiles x 128)

    unsigned b1[8] = {~0u, ~0u, ~0u, ~0u, ~0u, ~0u, ~0u, ~0u};
    unsigned b2[8] = {~0u, ~0u, ~0u, ~0u, ~0u, ~0u, ~0u, ~0u};

    // swap-free 2-deep pipeline: sets A (even tiles) and B (odd tiles)
    f16x8 Ah0 = ehp[fb + lane],        Ah1 = ehp[fb + 64 + lane];
    f16x8 Al0 = elp[fb + lane],        Al1 = elp[fb + 64 + lane];
    f16x8 Bh0 = ehp[fb + 128 + lane],  Bh1 = ehp[fb + 192 + lane];
    f16x8 Bl0 = elp[fb + 128 + lane],  Bl1 = elp[fb + 192 + lane];
    int onx = fb + 256 + lane;            // fragment index of tile t+2

#define COMPUTE(T, H0, H1, L0, L1) { \
        const float enk8 = enS8[(T) * 16 + col]; \
        f32x4 acch0  = {enk8, enk8, enk8, enk8}; \
        f32x4 accm0a = {0.f, 0.f, 0.f, 0.f}; \
        f32x4 accm0b = {0.f, 0.f, 0.f, 0.f}; \
        f32x4 acch1  = {enk8, enk8, enk8, enk8}; \
        f32x4 accm1a = {0.f, 0.f, 0.f, 0.f}; \
        f32x4 accm1b = {0.f, 0.f, 0.f, 0.f}; \
        acch0  = __builtin_amdgcn_mfma_f32_16x16x32_f16(ah0_0, H0, acch0,  0, 0, 0); \
        acch0  = __builtin_amdgcn_mfma_f32_16x16x32_f16(ah1_0, H1, acch0,  0, 0, 0); \
        accm0a = __builtin_amdgcn_mfma_f32_16x16x32_f16(al0_0, H0, accm0a, 0, 0, 0); \
        accm0a = __builtin_amdgcn_mfma_f32_16x16x32_f16(ah0_0, L0, accm0a, 0, 0, 0); \
        accm0b = __builtin_amdgcn_mfma_f32_16x16x32_f16(al1_0, H1, accm0b, 0, 0, 0); \
        accm0b = __builtin_amdgcn_mfma_f32_16x16x32_f16(ah1_0, L1, accm0b, 0, 0, 0); \
        acch1  = __builtin_amdgcn_mfma_f32_16x16x32_f16(ah0_1, H0, acch1,  0, 0, 0); \
        acch1  = __builtin_amdgcn_mfma_f32_16x16x32_f16(ah1_1, H1, acch1,  0, 0, 0); \
        accm1a = __builtin_amdgcn_mfma_f32_16x16x32_f16(al0_1, H0, accm1a, 0, 0, 0); \
        accm1a = __builtin_amdgcn_mfma_f32_16x16x32_f16(ah0_1, L0, accm1a, 0, 0, 0); \
        accm1b = __builtin_amdgcn_mfma_f32_16x16x32_f16(al1_1, H1, accm1b, 0, 0, 0); \
        accm1b = __builtin_amdgcn_mfma_f32_16x16x32_f16(ah1_1, L1, accm1b, 0, 0, 0); \
        _Pragma("unroll") \
        for (int j = 0; j < 4; ++j) { \
            float scb = fmaf(accm0a[j] + accm0b[j], INV_ELS, acch0[j]); \
            unsigned u = (__float_as_uint(scb) & 0xFFFFFFE0u) | (unsigned)(T); \
            b2[j] = min(b2[j], max(u, b1[j])); \
            b1[j] = min(b1[j], u); \
            float scb1 = fmaf(accm1a[j] + accm1b[j], INV_ELS, acch1[j]); \
            unsigned u1 = (__float_as_uint(scb1) & 0xFFFFFFE0u) | (unsigned)(T); \
            b2[j + 4] = min(b2[j + 4], max(u1, b1[j + 4])); \
            b1[j + 4] = min(b1[j + 4], u1); \
        } }

#pragma unroll 1
    for (int t = 0; t < 16; t += 2) {
        COMPUTE(half * 16 + t, Ah0, Ah1, Al0, Al1)
        // reload set A with tile t+2 (tail iters read harmless ws data)
        Ah0 = ehp[onx]; Ah1 = ehp[onx + 64];
        Al0 = elp[onx]; Al1 = elp[onx + 64];
        COMPUTE(half * 16 + t + 1, Bh0, Bh1, Bl0, Bl1)
        Bh0 = ehp[onx + 128]; Bh1 = ehp[onx + 192];
        Bl0 = elp[onx + 128]; Bl1 = elp[onx + 192];
        onx += 256;
    }
#undef COMPUTE

    // rebuild (masked-dist, k) as u64 and lex-merge top-2 across 16 lanes
    u64 q1[8], q2[8];
#pragma unroll
    for (int s = 0; s < 8; ++s) {
        q1[s] = ((u64)(b1[s] & 0xFFFFFFE0u) << 32) | (unsigned)((b1[s] & 31u) * 16 + col);
        q2[s] = ((u64)(b2[s] & 0xFFFFFFE0u) << 32) | (unsigned)((b2[s] & 31u) * 16 + col);
    }
#pragma unroll
    for (int m = 1; m <= 8; m <<= 1) {
#pragma unroll
        for (int s = 0; s < 8; ++s) {
            u64 qa = __shfl_xor(q1[s], m);
            u64 qb = __shfl_xor(q2[s], m);
            u64 lo = q1[s] < qa ? q1[s] : qa;
            u64 hi = q1[s] < qa ? qa : q1[s];
            u64 s2 = q2[s] < qb ? q2[s] : qb;
            q1[s] = lo;
            q2[s] = hi < s2 ? hi : s2;
        }
    }
    {
        const int j = lane & 15;
        if (j < 4) {                      // static-index extraction (rule #20)
            u64 s1a = j == 0 ? q1[0] : j == 1 ? q1[1] : j == 2 ? q1[2] : q1[3];
            u64 s2a = j == 0 ? q2[0] : j == 1 ? q2[1] : j == 2 ? q2[2] : q2[3];
            u64 s1b = j == 0 ? q1[4] : j == 1 ? q1[5] : j == 2 ? q1[6] : q1[7];
            u64 s2b = j == 0 ? q2[4] : j == 1 ? q2[5] : j == 2 ? q2[6] : q2[7];
            const int v0 = vb + g4 * 4 + j;
            const int v1 = vb + 16 + g4 * 4 + j;
            sdf1[half][v0] = __uint_as_float((unsigned)(s1a >> 32));
            sdf2[half][v0] = __uint_as_float((unsigned)(s2a >> 32));
            k1a[half][v0]  = (int)(s1a & 0x1FFu);
            k2a[half][v0]  = (int)(s2a & 0x1FFu);
            sdf1[half][v1] = __uint_as_float((unsigned)(s1b >> 32));
            sdf2[half][v1] = __uint_as_float((unsigned)(s2b >> 32));
            k1a[half][v1]  = (int)(s1b & 0x1FFu);
            k2a[half][v1]  = (int)(s2b & 0x1FFu);
        }
    }
    __syncthreads();

    // merge the two code-halves per vector (lex (dist,k): half-0 ks lower)
    if (tid < VPB) {
        const float a1 = sdf1[0][tid]; const int ka1 = k1a[0][tid];
        const float a2 = sdf2[0][tid]; const int ka2 = k2a[0][tid];
        const float c1 = sdf1[1][tid]; const int kc1 = k1a[1][tid];
        const float c2 = sdf2[1][tid]; const int kc2 = k2a[1][tid];
        const bool afirst = (a1 < c1) || (a1 == c1 && ka1 < kc1);
        const float f1 = afirst ? a1 : c1;  const int fk1 = afirst ? ka1 : kc1;
        const float u  = afirst ? a2 : c2;  const int uk  = afirst ? ka2 : kc2; // winner's 2nd
        const float w  = afirst ? c1 : a1;  const int wk  = afirst ? kc1 : ka1; // loser's 1st
        const bool usec = (u < w) || (u == w && uk < wk);
        cand[tid][0] = fk1;               sdfm[tid][0] = f1;
        cand[tid][1] = usec ? uk : wk;    sdfm[tid][1] = usec ? u : w;
    }
    __syncthreads();

    // conditional exact rescore (reference-exact chain; exact en from ws)
    if (tid < 2 * VPB) {
        const int v = tid >> 1, cc = tid & 1;
        float res = sdfm[v][cc];          // biased fallback (consistent pair)
        if (sdfm[v][1] - sdfm[v][0] <= GAP_THR) {
            const int k = cand[v][cc];
            const float* xr = x + xbase + v * DIM;
            const float* er = ws_ro + WS_EMBT + k * 64;
            float zn = 0.f, dot = 0.f;
#pragma unroll
            for (int d = 0; d < DIM; ++d) {
                float xv = xr[d];
                zn  = fmaf(xv, xv, zn);
                dot = fmaf(xv, er[d], dot);
            }
            res = fmaf(-2.0f, dot, zn + ws_ro[WS_EN + k]);
        }
        exd[v][cc] = res;
    }
    __syncthreads();
    if (tid < VPB) {
        const int k0 = cand[tid][0], k1 = cand[tid][1];
        const float d0 = exd[tid][0], d1 = exd[tid][1];
        const bool take2 = (d1 < d0) || (d1 == d0 && k1 < k0);
        bksel[tid] = take2 ? k1 : k0;
    }
    __syncthreads();

    // epilogue: thread -> (vector v16, dim-block j16); q from embT rows
    const int v16 = tid >> 2;             // 0..127
    const int j16 = (tid & 3) * 16;
    const int bk  = bksel[v16];
    const int gvec = blockIdx.x * VPB + v16;
    const float*  xg  = x + (size_t)gvec * DIM + j16;
    float*        og  = out + (size_t)gvec * DIM + j16;
    const float4* et4 = (const float4*)(ws_ro + WS_EMBT + bk * 64);

    float lossLocal = 0.f;
#pragma unroll
    for (int c = 0; c < 4; ++c) {
        float4 q  = et4[(tid & 3) * 4 + c];
        *(float4*)(og + c * 4) = q;
        float4 xa = *(const float4*)(xg + c * 4);
        float a;
        a = q.x - xa.x; lossLocal = fmaf(a, a, lossLocal);
        a = q.y - xa.y; lossLocal = fmaf(a, a, lossLocal);
        a = q.z - xa.z; lossLocal = fmaf(a, a, lossLocal);
        a = q.w - xa.w; lossLocal = fmaf(a, a, lossLocal);
    }

    // block-reduce loss -> one partial store per block (no atomics)
#pragma unroll
    for (int off = 32; off; off >>= 1) lossLocal += __shfl_down(lossLocal, off, 64);
    if (lane == 0) swl[wid] = lossLocal;
    __syncthreads();
    if (tid == 0) {
        float s = 0.f;
#pragma unroll
        for (int i = 0; i < 8; ++i) s += swl[i];
        part[WS_PART + blockIdx.x] = s;
    }
}

// Finish: reduce 512 per-block partials, write the loss element.
__global__ __launch_bounds__(256, 1) void finish_kernel(const float* __restrict__ part,
                                                        float* __restrict__ out) {
    __shared__ float sw[4];
    const int tid = threadIdx.x, lane = tid & 63, wid = tid >> 6;
    float s = part[WS_PART + tid] + part[WS_PART + tid + 256];
#pragma unroll
    for (int off = 32; off; off >>= 1) s += __shfl_down(s, off, 64);
    if (lane == 0) sw[wid] = s;
    __syncthreads();
    if (tid == 0) {
        float total = sw[0] + sw[1] + sw[2] + sw[3];
        out[(size_t)NVEC * DIM] = 2.0f * total / (float)((size_t)NVEC * DIM);
    }
}

extern "C" void kernel_launch(void* const* d_in, const int* in_sizes, int n_in,
                              void* d_out, int out_size, void* d_ws, size_t ws_size,
                              hipStream_t stream) {
    const float* x   = (const float*)d_in[0];
    const float* emb = (const float*)d_in[1];
    float* out = (float*)d_out;
    float* ws  = (float*)d_ws;

    prep_kernel<<<dim3(17), dim3(512), 0, stream>>>(emb, ws);
    vq_kernel<<<dim3(NBLK), dim3(512), 0, stream>>>(x, ws, out, ws);
    finish_kernel<<<dim3(1), dim3(256), 0, stream>>>(ws, out);
}